// Round 6
// baseline (1213.174 us; speedup 1.0000x reference)
//
#include <hip/hip_runtime.h>

// RK4 neural-ODE: f(y) = tanh(y W1 + b1) W2 + b2;  3072 rows x 255 steps.
// Wave-synchronous, ONE row per wave at a time, 2 rows sequentially per wave.
//
// ROUND 10 == ROUND 7/8/9 resubmit (none ran: 2x acquisition timeout + 1x
// container failure). Theory: kill the AGPR copy tax.
// Evidence (R6 counters + arithmetic): VGPR_Count=100 with 128 weight floats
// per lane => weights were AGPR-packed (unified RF), v_accvgpr_read copies in
// the hot loop. R4's VGPR=80 + AGPR = 168 = exactly the waves_per_eu(3,3)
// budget; measured issue rate implies ~222 instr/eval vs ~140 of real math.
// Fix: waves_per_eu(2,2) => 256-reg budget, true demand ~160 fits ALL-VGPR.
// One row per wave (R6's 2-row ILP regressed: -27%); 128-thr blocks; each
// wave does 2 rows SEQUENTIALLY so 768 blocks x 2 waves = 3 blocks/CU =
// 6 waves/CU <= the (2,2) cap of 8 -- no block serialization round.
// Per-row math is bit-identical to the 913us R4 kernel (absmax must stay
// 0.015625). Post-mortem tell: VGPR_Count ~160-176 and dur ~650us confirms;
// VGPR ~100 again refutes.

typedef float f2 __attribute__((ext_vector_type(2)));
typedef float f4 __attribute__((ext_vector_type(4)));

__device__ __forceinline__ float rl(float v, int lane) {
  return __int_as_float(__builtin_amdgcn_readlane(__float_as_int(v), lane));
}
__device__ __forceinline__ f2 fma2(f2 a, f2 b, f2 c) {
  return __builtin_elementwise_fma(a, b, c);
}
// tanh(z) with z pre-scaled by 2*log2(e): tanh = 1 - 2/(2^z + 1)
__device__ __forceinline__ float tanh_scaled(float z) {
  float t = __builtin_amdgcn_exp2f(z);
  return fmaf(-2.0f, __builtin_amdgcn_rcpf(t + 1.0f), 1.0f);
}
// quad_perm xor-1 / xor-2 (VALU-pipe cross-lane)
__device__ __forceinline__ float dpp_xor1(float x) {
  return __int_as_float(__builtin_amdgcn_update_dpp(
      0, __float_as_int(x), 0xB1, 0xF, 0xF, true));  // [1,0,3,2]
}
__device__ __forceinline__ float dpp_xor2(float x) {
  return __int_as_float(__builtin_amdgcn_update_dpp(
      0, __float_as_int(x), 0x4E, 0xF, 0xF, true));  // [2,3,0,1]
}
__device__ __forceinline__ f2 ldW2(const float* W2, int j, int d) {
  f2 r; r.x = W2[j * 32 + d]; r.y = W2[(j + 1) * 32 + d]; return r;
}
__device__ __forceinline__ float bperm(int addr, float v) {
  return __int_as_float(__builtin_amdgcn_ds_bpermute(addr, __float_as_int(v)));
}

#define REP32(X) \
  X(0) X(1) X(2) X(3) X(4) X(5) X(6) X(7) X(8) X(9) X(10) X(11) X(12) X(13) \
  X(14) X(15) X(16) X(17) X(18) X(19) X(20) X(21) X(22) X(23) X(24) X(25)   \
  X(26) X(27) X(28) X(29) X(30) X(31)

__global__ void __launch_bounds__(128)
__attribute__((amdgpu_waves_per_eu(2, 2)))
rk4_ode_kernel(const float* __restrict__ fp,   // [3072,32]
               const float* __restrict__ ts,   // [256]
               const float* __restrict__ W1,   // [32,128]
               const float* __restrict__ b1,   // [128]
               const float* __restrict__ W2,   // [128,32]
               const float* __restrict__ b2,   // [32]
               float* __restrict__ out) {      // [3072,256,32]
  // per-wave h buffer: 8 chunks of 16 floats at stride 20 (bank stagger)
  __shared__ float smem[2 * 160];

  const int tid = threadIdx.x;
  const int wv  = tid >> 6;                   // 0..1
  const int p   = tid & 63;

  const int g  = (p & 3) | ((p >> 5) << 2);   // j-group: lane bits {0,1,5}
  const int j0 = g << 4;                      // 16 j's per group
  const int d0 = p & 0x1C;                    // outputs d0|m, m=0..3

  const float C = 2.885390081777926814f;      // 2*log2(e) folded into W1/b1

  // ---- W1: lane p produces h_{2p}, h_{2p+1}; packed col-pairs, pre-scaled ----
  const float2* W1v = reinterpret_cast<const float2*>(W1);
#define LOADW1(dd) f2 w1_##dd; { const float2 t_ = W1v[dd * 64 + p]; \
                                 w1_##dd.x = t_.x * C; w1_##dd.y = t_.y * C; }
  REP32(LOADW1)
#undef LOADW1
  const float2 b1t = reinterpret_cast<const float2*>(b1)[p];
  const f2 b1v = {b1t.x * C, b1t.y * C};

  // ---- W2: rows [j0, j0+16) for 4 outputs d0|m, as j-pair f2 regs ----
#define LW2(m) \
  const f2 w2_##m##_0 = ldW2(W2, j0 + 0,  d0 | m); \
  const f2 w2_##m##_1 = ldW2(W2, j0 + 2,  d0 | m); \
  const f2 w2_##m##_2 = ldW2(W2, j0 + 4,  d0 | m); \
  const f2 w2_##m##_3 = ldW2(W2, j0 + 6,  d0 | m); \
  const f2 w2_##m##_4 = ldW2(W2, j0 + 8,  d0 | m); \
  const f2 w2_##m##_5 = ldW2(W2, j0 + 10, d0 | m); \
  const f2 w2_##m##_6 = ldW2(W2, j0 + 12, d0 | m); \
  const f2 w2_##m##_7 = ldW2(W2, j0 + 14, d0 | m);
  LW2(0) LW2(1) LW2(2) LW2(3)
#undef LW2
  const float b2l = b2[p & 31];

  // h LDS addressing: h_j stored at float index 20*(j>>4) + (j&15)
  float* hwbase = &smem[wv * 160];
  float* hwr    = hwbase + 20 * (p >> 3) + 2 * (p & 7);   // write f2 (j=2p,2p+1)
  const f4* hrd = reinterpret_cast<const f4*>(hwbase + 20 * g); // 4x b128 reads
  const int pairaddr = (p ^ 32) << 2;

  // ---- two rows, integrated sequentially (weights stay resident) ----
  for (int rr = 0; rr < 2; ++rr) {
    const int row = blockIdx.x * 4 + wv * 2 + rr;

    // RK4 state: lane p holds dim d = p&31 (valid on all 64 lanes)
    float y0   = fp[row * 32 + (p & 31)];
    float ycur = y0;
    float kacc = 0.0f;

    float* outrow = out + (size_t)row * (256 * 32);
    if (p < 32) outrow[p] = y0;

    for (int t = 0; t < 255; ++t) {
      const float dt = ts[t + 1] - ts[t];
#pragma unroll
      for (int st = 0; st < 4; ++st) {
        // ---- phase 1: z = C*(b1 + y.W1) for cols 2p,2p+1 (two acc chains) ----
        f2 ae = b1v, ao = {0.0f, 0.0f};
#define P1(dd) { const float s_ = rl(ycur, dd); const f2 ss = {s_, s_};      \
                 if ((dd) & 1) ao = fma2(ss, w1_##dd, ao);                   \
                 else          ae = fma2(ss, w1_##dd, ae); }
        REP32(P1)
#undef P1
        const f2 a = ae + ao;
        *reinterpret_cast<f2*>(hwr) = (f2){tanh_scaled(a.x), tanh_scaled(a.y)};
        __builtin_amdgcn_wave_barrier();          // write before reads

        // ---- phase 2: 16 h-floats for my j-group vs 4 output columns ----
        f2 acc0 = {0,0}, acc1 = {0,0}, acc2 = {0,0}, acc3 = {0,0};
        {
          const f4 r_0 = hrd[0], r_1 = hrd[1];
#define ACCA(m) acc##m = fma2(r_0.xy, w2_##m##_0, acc##m); \
                acc##m = fma2(r_0.zw, w2_##m##_1, acc##m); \
                acc##m = fma2(r_1.xy, w2_##m##_2, acc##m); \
                acc##m = fma2(r_1.zw, w2_##m##_3, acc##m);
          ACCA(0) ACCA(1) ACCA(2) ACCA(3)
#undef ACCA
          const f4 r_2 = hrd[2], r_3 = hrd[3];
#define ACCB(m) acc##m = fma2(r_2.xy, w2_##m##_4, acc##m); \
                acc##m = fma2(r_2.zw, w2_##m##_5, acc##m); \
                acc##m = fma2(r_3.xy, w2_##m##_6, acc##m); \
                acc##m = fma2(r_3.zw, w2_##m##_7, acc##m);
          ACCB(0) ACCB(1) ACCB(2) ACCB(3)
#undef ACCB
        }
        __builtin_amdgcn_wave_barrier();          // reads before next write

        // ---- combine group partials: ^1,^2 via DPP (VALU), select, ^32 ----
        float k0 = acc0.x + acc0.y, k1 = acc1.x + acc1.y;
        float k2 = acc2.x + acc2.y, k3 = acc3.x + acc3.y;
        k0 += dpp_xor1(k0); k1 += dpp_xor1(k1);
        k2 += dpp_xor1(k2); k3 += dpp_xor1(k3);
        k0 += dpp_xor2(k0); k1 += dpp_xor2(k1);
        k2 += dpp_xor2(k2); k3 += dpp_xor2(k3);
        const float s01 = (p & 1) ? k1 : k0;
        const float s23 = (p & 1) ? k3 : k2;
        const float ks  = (p & 2) ? s23 : s01;    // my output's quad partial
        const float k = ks + b2l + bperm(pairaddr, ks);

        // ---- RK4 stage combination ----
        if (st == 0) {
          kacc = k;                   ycur = fmaf(0.5f * dt, k, y0);
        } else if (st == 1) {
          kacc = fmaf(2.0f, k, kacc); ycur = fmaf(0.5f * dt, k, y0);
        } else if (st == 2) {
          kacc = fmaf(2.0f, k, kacc); ycur = fmaf(dt, k, y0);
        } else {
          kacc = kacc + k;
          y0   = fmaf(dt * (1.0f / 6.0f), kacc, y0);
          ycur = y0;
        }
      }
      if (p < 32) outrow[(t + 1) * 32 + p] = y0;
    }
  }
}

extern "C" void kernel_launch(void* const* d_in, const int* in_sizes, int n_in,
                              void* d_out, int out_size, void* d_ws, size_t ws_size,
                              hipStream_t stream) {
  const float* fp = (const float*)d_in[0];   // first_point [3,1024,32]
  const float* ts = (const float*)d_in[1];   // time_steps [256]
  const float* W1 = (const float*)d_in[2];   // [32,128]
  const float* b1 = (const float*)d_in[3];   // [128]
  const float* W2 = (const float*)d_in[4];   // [128,32]
  const float* b2 = (const float*)d_in[5];   // [32]
  float* out = (float*)d_out;                // [3,1024,256,32]

  rk4_ode_kernel<<<768, 128, 0, stream>>>(fp, ts, W1, b1, W2, b2, out);
}

// Round 8
// 910.898 us; speedup vs baseline: 1.3318x; 1.3318x over previous
//
#include <hip/hip_runtime.h>

// RK4 neural-ODE: f(y) = tanh(y W1 + b1) W2 + b2;  3072 rows x 255 steps.
// One wave per row, wave-synchronous. R4 geometry restored (768x256, 12
// waves/CU = 3/SIMD balanced, waves_per_eu(3,3)).
//
// ROUND 12 == ROUND 11 resubmit (R11 never ran: acquisition timeout).
// VGPR-PIN experiment on top of byte-identical R4 math.
// Evidence: R6 (waves_per_eu(2,2), 256-reg budget) still gave VGPR_Count=88
// => the allocator AGPR-packs the 128 weight floats by heuristic, not by
// budget; attributes cannot force them into arch VGPRs. R6/R7 also showed
// 128-thr geometry (1.5 waves/SIMD, 2/2/1/1 imbalance) loses ~30% vs R4's
// 3/SIMD. Fix under test: empty volatile inline-asm inside the t-loop with
// all 64 weight f2's as "v"-constrained inputs -- at that point each weight
// must sit in an arch VGPR pair; since they're loop-invariant and demand
// (~160) fits the (3,3) budget (~170), the allocator should keep them there
// permanently, killing the per-use v_accvgpr_read copy tax (~80 instr/eval
// of the measured ~220 vs ~140 hand-counted).
// Tells: VGPR ~150-168 + dur ~650us confirms; VGPR <=100 + dur ~913 refutes
// (-> disasm next); dur >=1500 + FETCH explosion = scratch spill -> revert.

typedef float f2 __attribute__((ext_vector_type(2)));
typedef float f4 __attribute__((ext_vector_type(4)));

__device__ __forceinline__ float rl(float v, int lane) {
  return __int_as_float(__builtin_amdgcn_readlane(__float_as_int(v), lane));
}
__device__ __forceinline__ f2 fma2(f2 a, f2 b, f2 c) {
  return __builtin_elementwise_fma(a, b, c);
}
// tanh(z) with z pre-scaled by 2*log2(e): tanh = 1 - 2/(2^z + 1)
__device__ __forceinline__ float tanh_scaled(float z) {
  float t = __builtin_amdgcn_exp2f(z);
  return fmaf(-2.0f, __builtin_amdgcn_rcpf(t + 1.0f), 1.0f);
}
// quad_perm xor-1 / xor-2 (VALU-pipe cross-lane)
__device__ __forceinline__ float dpp_xor1(float x) {
  return __int_as_float(__builtin_amdgcn_update_dpp(
      0, __float_as_int(x), 0xB1, 0xF, 0xF, true));  // [1,0,3,2]
}
__device__ __forceinline__ float dpp_xor2(float x) {
  return __int_as_float(__builtin_amdgcn_update_dpp(
      0, __float_as_int(x), 0x4E, 0xF, 0xF, true));  // [2,3,0,1]
}
__device__ __forceinline__ f2 ldW2(const float* W2, int j, int d) {
  f2 r; r.x = W2[j * 32 + d]; r.y = W2[(j + 1) * 32 + d]; return r;
}

#define REP32(X) \
  X(0) X(1) X(2) X(3) X(4) X(5) X(6) X(7) X(8) X(9) X(10) X(11) X(12) X(13) \
  X(14) X(15) X(16) X(17) X(18) X(19) X(20) X(21) X(22) X(23) X(24) X(25)   \
  X(26) X(27) X(28) X(29) X(30) X(31)

__global__ void __launch_bounds__(256)
__attribute__((amdgpu_waves_per_eu(3, 3)))
rk4_ode_kernel(const float* __restrict__ fp,   // [3072,32]
               const float* __restrict__ ts,   // [256]
               const float* __restrict__ W1,   // [32,128]
               const float* __restrict__ b1,   // [128]
               const float* __restrict__ W2,   // [128,32]
               const float* __restrict__ b2,   // [32]
               float* __restrict__ out) {      // [3072,256,32]
  // per-wave h buffer: 8 chunks of 16 floats at stride 20 (bank stagger)
  __shared__ float smem[4 * 160];

  const int tid = threadIdx.x;
  const int wv  = tid >> 6;
  const int p   = tid & 63;
  const int row = blockIdx.x * 4 + wv;

  const int g  = (p & 3) | ((p >> 5) << 2);   // j-group: lane bits {0,1,5}
  const int j0 = g << 4;                      // 16 j's per group
  const int d0 = p & 0x1C;                    // outputs d0|m, m=0..3 (q=bits{2,3,4})

  const float C = 2.885390081777926814f;      // 2*log2(e) folded into W1/b1

  // ---- W1: lane p produces h_{2p}, h_{2p+1}; packed col-pairs, pre-scaled ----
  const float2* W1v = reinterpret_cast<const float2*>(W1);
#define LOADW1(dd) f2 w1_##dd; { const float2 t_ = W1v[dd * 64 + p]; \
                                 w1_##dd.x = t_.x * C; w1_##dd.y = t_.y * C; }
  REP32(LOADW1)
#undef LOADW1
  const float2 b1t = reinterpret_cast<const float2*>(b1)[p];
  const f2 b1v = {b1t.x * C, b1t.y * C};

  // ---- W2: rows [j0, j0+16) for 4 outputs d0|m, as j-pair f2 regs ----
#define LW2(m) \
  f2 w2_##m##_0 = ldW2(W2, j0 + 0,  d0 | m); \
  f2 w2_##m##_1 = ldW2(W2, j0 + 2,  d0 | m); \
  f2 w2_##m##_2 = ldW2(W2, j0 + 4,  d0 | m); \
  f2 w2_##m##_3 = ldW2(W2, j0 + 6,  d0 | m); \
  f2 w2_##m##_4 = ldW2(W2, j0 + 8,  d0 | m); \
  f2 w2_##m##_5 = ldW2(W2, j0 + 10, d0 | m); \
  f2 w2_##m##_6 = ldW2(W2, j0 + 12, d0 | m); \
  f2 w2_##m##_7 = ldW2(W2, j0 + 14, d0 | m);
  LW2(0) LW2(1) LW2(2) LW2(3)
#undef LW2
  const float b2l = b2[p & 31];

  // ---- RK4 state: lane p holds dim d = p&31 (valid on all 64 lanes) ----
  float y0   = fp[row * 32 + (p & 31)];
  float ycur = y0;
  float kacc = 0.0f;

  float* outrow = out + (size_t)row * (256 * 32);
  if (p < 32) outrow[p] = y0;

  // h LDS addressing: h_j stored at float index 20*(j>>4) + (j&15)
  float* hwbase = &smem[wv * 160];
  float* hwr    = hwbase + 20 * (p >> 3) + 2 * (p & 7);   // write f2 (j=2p,2p+1)
  const f4* hrd = reinterpret_cast<const f4*>(hwbase + 20 * g); // 4x b128 reads
  const int pairaddr = (p ^ 32) << 2;

  for (int t = 0; t < 255; ++t) {
    // ---- VGPR pin: force every weight into an arch VGPR pair here. ----
    // Empty volatile asm; zero instructions, but "v" constraints require
    // arch-VGPR residence at this point each iteration, steering the
    // allocator away from AGPR-packing the loop-invariant weights.
    asm volatile("" :: "v"(w1_0), "v"(w1_1), "v"(w1_2), "v"(w1_3),
                       "v"(w1_4), "v"(w1_5), "v"(w1_6), "v"(w1_7));
    asm volatile("" :: "v"(w1_8), "v"(w1_9), "v"(w1_10), "v"(w1_11),
                       "v"(w1_12), "v"(w1_13), "v"(w1_14), "v"(w1_15));
    asm volatile("" :: "v"(w1_16), "v"(w1_17), "v"(w1_18), "v"(w1_19),
                       "v"(w1_20), "v"(w1_21), "v"(w1_22), "v"(w1_23));
    asm volatile("" :: "v"(w1_24), "v"(w1_25), "v"(w1_26), "v"(w1_27),
                       "v"(w1_28), "v"(w1_29), "v"(w1_30), "v"(w1_31));
    asm volatile("" :: "v"(w2_0_0), "v"(w2_0_1), "v"(w2_0_2), "v"(w2_0_3),
                       "v"(w2_0_4), "v"(w2_0_5), "v"(w2_0_6), "v"(w2_0_7));
    asm volatile("" :: "v"(w2_1_0), "v"(w2_1_1), "v"(w2_1_2), "v"(w2_1_3),
                       "v"(w2_1_4), "v"(w2_1_5), "v"(w2_1_6), "v"(w2_1_7));
    asm volatile("" :: "v"(w2_2_0), "v"(w2_2_1), "v"(w2_2_2), "v"(w2_2_3),
                       "v"(w2_2_4), "v"(w2_2_5), "v"(w2_2_6), "v"(w2_2_7));
    asm volatile("" :: "v"(w2_3_0), "v"(w2_3_1), "v"(w2_3_2), "v"(w2_3_3),
                       "v"(w2_3_4), "v"(w2_3_5), "v"(w2_3_6), "v"(w2_3_7));

    const float dt = ts[t + 1] - ts[t];
#pragma unroll
    for (int st = 0; st < 4; ++st) {
      // ---- phase 1: z = C*(b1 + y.W1) for cols 2p,2p+1 (two acc chains) ----
      f2 ae = b1v, ao = {0.0f, 0.0f};
#define P1(dd) { const float s_ = rl(ycur, dd); const f2 ss = {s_, s_};      \
                 if ((dd) & 1) ao = fma2(ss, w1_##dd, ao);                   \
                 else          ae = fma2(ss, w1_##dd, ae); }
      REP32(P1)
#undef P1
      const f2 a = ae + ao;
      *reinterpret_cast<f2*>(hwr) = (f2){tanh_scaled(a.x), tanh_scaled(a.y)};
      __builtin_amdgcn_wave_barrier();          // write before reads

      // ---- phase 2: 16 h-floats for my j-group vs 4 output columns ----
      f2 acc0 = {0,0}, acc1 = {0,0}, acc2 = {0,0}, acc3 = {0,0};
      {
        const f4 r_0 = hrd[0], r_1 = hrd[1];
#define ACCA(m) acc##m = fma2(r_0.xy, w2_##m##_0, acc##m); \
                acc##m = fma2(r_0.zw, w2_##m##_1, acc##m); \
                acc##m = fma2(r_1.xy, w2_##m##_2, acc##m); \
                acc##m = fma2(r_1.zw, w2_##m##_3, acc##m);
        ACCA(0) ACCA(1) ACCA(2) ACCA(3)
#undef ACCA
        const f4 r_2 = hrd[2], r_3 = hrd[3];
#define ACCB(m) acc##m = fma2(r_2.xy, w2_##m##_4, acc##m); \
                acc##m = fma2(r_2.zw, w2_##m##_5, acc##m); \
                acc##m = fma2(r_3.xy, w2_##m##_6, acc##m); \
                acc##m = fma2(r_3.zw, w2_##m##_7, acc##m);
        ACCB(0) ACCB(1) ACCB(2) ACCB(3)
#undef ACCB
      }
      __builtin_amdgcn_wave_barrier();          // reads before next write

      // ---- combine group partials: ^1,^2 via DPP (VALU), then select, ^32 ----
      float k0 = acc0.x + acc0.y, k1 = acc1.x + acc1.y;
      float k2 = acc2.x + acc2.y, k3 = acc3.x + acc3.y;
      k0 += dpp_xor1(k0); k1 += dpp_xor1(k1); k2 += dpp_xor1(k2); k3 += dpp_xor1(k3);
      k0 += dpp_xor2(k0); k1 += dpp_xor2(k1); k2 += dpp_xor2(k2); k3 += dpp_xor2(k3);
      const float s01 = (p & 1) ? k1 : k0;
      const float s23 = (p & 1) ? k3 : k2;
      const float ks  = (p & 2) ? s23 : s01;    // my output's quad partial
      const float k = ks + b2l + __int_as_float(
          __builtin_amdgcn_ds_bpermute(pairaddr, __float_as_int(ks)));

      // ---- RK4 stage combination ----
      if (st == 0) {
        kacc = k;                   ycur = fmaf(0.5f * dt, k, y0);
      } else if (st == 1) {
        kacc = fmaf(2.0f, k, kacc); ycur = fmaf(0.5f * dt, k, y0);
      } else if (st == 2) {
        kacc = fmaf(2.0f, k, kacc); ycur = fmaf(dt, k, y0);
      } else {
        kacc = kacc + k;
        y0   = fmaf(dt * (1.0f / 6.0f), kacc, y0);
        ycur = y0;
      }
    }
    if (p < 32) outrow[(t + 1) * 32 + p] = y0;
  }
}

extern "C" void kernel_launch(void* const* d_in, const int* in_sizes, int n_in,
                              void* d_out, int out_size, void* d_ws, size_t ws_size,
                              hipStream_t stream) {
  const float* fp = (const float*)d_in[0];   // first_point [3,1024,32]
  const float* ts = (const float*)d_in[1];   // time_steps [256]
  const float* W1 = (const float*)d_in[2];   // [32,128]
  const float* b1 = (const float*)d_in[3];   // [128]
  const float* W2 = (const float*)d_in[4];   // [128,32]
  const float* b2 = (const float*)d_in[5];   // [32]
  float* out = (float*)d_out;                // [3,1024,256,32]

  rk4_ode_kernel<<<768, 256, 0, stream>>>(fp, ts, W1, b1, W2, b2, out);
}

// Round 11
// 823.791 us; speedup vs baseline: 1.4727x; 1.1057x over previous
//
#include <hip/hip_runtime.h>

// RK4 neural-ODE: f(y) = tanh(y W1 + b1) W2 + b2;  3072 rows x 255 steps.
// One wave per row, wave-synchronous. 768x256, waves_per_eu(3,3) (R8 best).
//
// ROUND 15 == ROUND 13/14 resubmit (neither ran: acquisition timeouts).
// Kill the readlane broadcast.
// R8 post-mortem: VGPR pin neutral (910.9 vs 913.1), VGPR_Count stuck at 84
// => allocator copies AGPR weights to temps at each use; attribute/pin levers
// dead. R8 arithmetic: 2252 cy/eval at 76.5% busy => ~287 VALU slots/wave-eval
// vs ~126 hand-counted. Gap = 128 AGPR-copies + 32 readlane/SGPR-broadcast
// overhead, OR readlane at quarter rate (256 cy). Common removable piece: the
// 32 v_readlanes. This round: y broadcast via LDS instead -- all lanes write
// ycur to a per-wave 32-float buffer (2-way same-addr dup = free, m136), next
// stage reads 8x uniform ds_read_b128 (DS pipe, off VALU). Accumulation order
// bit-identical (same even/odd chains) => absmax must stay 0.015625.
// Predict: dur 600-650 (readlane was 1/4-rate) or 810-830 (full-rate);
// refute if <5% delta => gap is pure AGPR copy tax => next: scalar v_fma_f32
// (VOP3 reads AGPRs directly; VOP3P may not).

typedef float f2 __attribute__((ext_vector_type(2)));
typedef float f4 __attribute__((ext_vector_type(4)));

__device__ __forceinline__ f2 fma2(f2 a, f2 b, f2 c) {
  return __builtin_elementwise_fma(a, b, c);
}
// tanh(z) with z pre-scaled by 2*log2(e): tanh = 1 - 2/(2^z + 1)
__device__ __forceinline__ float tanh_scaled(float z) {
  float t = __builtin_amdgcn_exp2f(z);
  return fmaf(-2.0f, __builtin_amdgcn_rcpf(t + 1.0f), 1.0f);
}
// quad_perm xor-1 / xor-2 (VALU-pipe cross-lane)
__device__ __forceinline__ float dpp_xor1(float x) {
  return __int_as_float(__builtin_amdgcn_update_dpp(
      0, __float_as_int(x), 0xB1, 0xF, 0xF, true));  // [1,0,3,2]
}
__device__ __forceinline__ float dpp_xor2(float x) {
  return __int_as_float(__builtin_amdgcn_update_dpp(
      0, __float_as_int(x), 0x4E, 0xF, 0xF, true));  // [2,3,0,1]
}
__device__ __forceinline__ f2 ldW2(const float* W2, int j, int d) {
  f2 r; r.x = W2[j * 32 + d]; r.y = W2[(j + 1) * 32 + d]; return r;
}

#define REP32(X) \
  X(0) X(1) X(2) X(3) X(4) X(5) X(6) X(7) X(8) X(9) X(10) X(11) X(12) X(13) \
  X(14) X(15) X(16) X(17) X(18) X(19) X(20) X(21) X(22) X(23) X(24) X(25)   \
  X(26) X(27) X(28) X(29) X(30) X(31)

__global__ void __launch_bounds__(256)
__attribute__((amdgpu_waves_per_eu(3, 3)))
rk4_ode_kernel(const float* __restrict__ fp,   // [3072,32]
               const float* __restrict__ ts,   // [256]
               const float* __restrict__ W1,   // [32,128]
               const float* __restrict__ b1,   // [128]
               const float* __restrict__ W2,   // [128,32]
               const float* __restrict__ b2,   // [32]
               float* __restrict__ out) {      // [3072,256,32]
  // per-wave: h buffer (8 chunks of 16 floats at stride 20, bank stagger)
  // + y broadcast buffer (32 floats)
  __shared__ float smem[4 * 160 + 4 * 32];

  const int tid = threadIdx.x;
  const int wv  = tid >> 6;
  const int p   = tid & 63;
  const int row = blockIdx.x * 4 + wv;

  const int g  = (p & 3) | ((p >> 5) << 2);   // j-group: lane bits {0,1,5}
  const int j0 = g << 4;                      // 16 j's per group
  const int d0 = p & 0x1C;                    // outputs d0|m, m=0..3

  const float C = 2.885390081777926814f;      // 2*log2(e) folded into W1/b1

  // ---- W1: lane p produces h_{2p}, h_{2p+1}; packed col-pairs, pre-scaled ----
  const float2* W1v = reinterpret_cast<const float2*>(W1);
#define LOADW1(dd) f2 w1_##dd; { const float2 t_ = W1v[dd * 64 + p]; \
                                 w1_##dd.x = t_.x * C; w1_##dd.y = t_.y * C; }
  REP32(LOADW1)
#undef LOADW1
  const float2 b1t = reinterpret_cast<const float2*>(b1)[p];
  const f2 b1v = {b1t.x * C, b1t.y * C};

  // ---- W2: rows [j0, j0+16) for 4 outputs d0|m, as j-pair f2 regs ----
#define LW2(m) \
  const f2 w2_##m##_0 = ldW2(W2, j0 + 0,  d0 | m); \
  const f2 w2_##m##_1 = ldW2(W2, j0 + 2,  d0 | m); \
  const f2 w2_##m##_2 = ldW2(W2, j0 + 4,  d0 | m); \
  const f2 w2_##m##_3 = ldW2(W2, j0 + 6,  d0 | m); \
  const f2 w2_##m##_4 = ldW2(W2, j0 + 8,  d0 | m); \
  const f2 w2_##m##_5 = ldW2(W2, j0 + 10, d0 | m); \
  const f2 w2_##m##_6 = ldW2(W2, j0 + 12, d0 | m); \
  const f2 w2_##m##_7 = ldW2(W2, j0 + 14, d0 | m);
  LW2(0) LW2(1) LW2(2) LW2(3)
#undef LW2
  const float b2l = b2[p & 31];

  // ---- RK4 state: lane p holds dim d = p&31 (valid on all 64 lanes) ----
  float y0   = fp[row * 32 + (p & 31)];
  float ycur = y0;
  float kacc = 0.0f;

  float* outrow = out + (size_t)row * (256 * 32);
  if (p < 32) outrow[p] = y0;

  // h LDS addressing: h_j stored at float index 20*(j>>4) + (j&15)
  float* hwbase = &smem[wv * 160];
  float* hwr    = hwbase + 20 * (p >> 3) + 2 * (p & 7);   // write f2 (j=2p,2p+1)
  const f4* hrd = reinterpret_cast<const f4*>(hwbase + 20 * g); // 4x b128 reads
  // y broadcast buffer
  float* ybase  = &smem[640 + wv * 32];
  const f4* yrd = reinterpret_cast<const f4*>(ybase);
  const int pairaddr = (p ^ 32) << 2;

  // seed y broadcast (lanes p and p^32 write the same value: free 2-way dup)
  ybase[p & 31] = ycur;
  __builtin_amdgcn_wave_barrier();

  for (int t = 0; t < 255; ++t) {
    const float dt = ts[t + 1] - ts[t];
#pragma unroll
    for (int st = 0; st < 4; ++st) {
      // ---- phase 1: z = C*(b1 + y.W1) for cols 2p,2p+1 (two acc chains) ----
      // y broadcast: 8 uniform ds_read_b128 (DS pipe) replaces 32 readlanes
      const f4 yv_0 = yrd[0]; const f4 yv_1 = yrd[1];
      const f4 yv_2 = yrd[2]; const f4 yv_3 = yrd[3];
      const f4 yv_4 = yrd[4]; const f4 yv_5 = yrd[5];
      const f4 yv_6 = yrd[6]; const f4 yv_7 = yrd[7];
      f2 ae = b1v, ao = {0.0f, 0.0f};
#define P1Q(q, wa, wb, wc, wd) {                                        \
      { const f2 ss = {yv_##q.x, yv_##q.x}; ae = fma2(ss, wa, ae); }    \
      { const f2 ss = {yv_##q.y, yv_##q.y}; ao = fma2(ss, wb, ao); }    \
      { const f2 ss = {yv_##q.z, yv_##q.z}; ae = fma2(ss, wc, ae); }    \
      { const f2 ss = {yv_##q.w, yv_##q.w}; ao = fma2(ss, wd, ao); } }
      P1Q(0, w1_0,  w1_1,  w1_2,  w1_3)
      P1Q(1, w1_4,  w1_5,  w1_6,  w1_7)
      P1Q(2, w1_8,  w1_9,  w1_10, w1_11)
      P1Q(3, w1_12, w1_13, w1_14, w1_15)
      P1Q(4, w1_16, w1_17, w1_18, w1_19)
      P1Q(5, w1_20, w1_21, w1_22, w1_23)
      P1Q(6, w1_24, w1_25, w1_26, w1_27)
      P1Q(7, w1_28, w1_29, w1_30, w1_31)
#undef P1Q
      const f2 a = ae + ao;
      *reinterpret_cast<f2*>(hwr) = (f2){tanh_scaled(a.x), tanh_scaled(a.y)};
      __builtin_amdgcn_wave_barrier();          // h write before h reads

      // ---- phase 2: 16 h-floats for my j-group vs 4 output columns ----
      f2 acc0 = {0,0}, acc1 = {0,0}, acc2 = {0,0}, acc3 = {0,0};
      {
        const f4 r_0 = hrd[0], r_1 = hrd[1];
#define ACCA(m) acc##m = fma2(r_0.xy, w2_##m##_0, acc##m); \
                acc##m = fma2(r_0.zw, w2_##m##_1, acc##m); \
                acc##m = fma2(r_1.xy, w2_##m##_2, acc##m); \
                acc##m = fma2(r_1.zw, w2_##m##_3, acc##m);
        ACCA(0) ACCA(1) ACCA(2) ACCA(3)
#undef ACCA
        const f4 r_2 = hrd[2], r_3 = hrd[3];
#define ACCB(m) acc##m = fma2(r_2.xy, w2_##m##_4, acc##m); \
                acc##m = fma2(r_2.zw, w2_##m##_5, acc##m); \
                acc##m = fma2(r_3.xy, w2_##m##_6, acc##m); \
                acc##m = fma2(r_3.zw, w2_##m##_7, acc##m);
        ACCB(0) ACCB(1) ACCB(2) ACCB(3)
#undef ACCB
      }
      __builtin_amdgcn_wave_barrier();          // h reads before next h write

      // ---- combine group partials: ^1,^2 via DPP (VALU), select, then ^32 ----
      float k0 = acc0.x + acc0.y, k1 = acc1.x + acc1.y;
      float k2 = acc2.x + acc2.y, k3 = acc3.x + acc3.y;
      k0 += dpp_xor1(k0); k1 += dpp_xor1(k1); k2 += dpp_xor1(k2); k3 += dpp_xor1(k3);
      k0 += dpp_xor2(k0); k1 += dpp_xor2(k1); k2 += dpp_xor2(k2); k3 += dpp_xor2(k3);
      const float s01 = (p & 1) ? k1 : k0;
      const float s23 = (p & 1) ? k3 : k2;
      const float ks  = (p & 2) ? s23 : s01;    // my output's quad partial
      const float k = ks + b2l + __int_as_float(
          __builtin_amdgcn_ds_bpermute(pairaddr, __float_as_int(ks)));

      // ---- RK4 stage combination ----
      if (st == 0) {
        kacc = k;                   ycur = fmaf(0.5f * dt, k, y0);
      } else if (st == 1) {
        kacc = fmaf(2.0f, k, kacc); ycur = fmaf(0.5f * dt, k, y0);
      } else if (st == 2) {
        kacc = fmaf(2.0f, k, kacc); ycur = fmaf(dt, k, y0);
      } else {
        kacc = kacc + k;
        y0   = fmaf(dt * (1.0f / 6.0f), kacc, y0);
        ycur = y0;
      }

      // publish y for next stage's broadcast (2-way same-addr dup: free)
      ybase[p & 31] = ycur;
      __builtin_amdgcn_wave_barrier();          // y write before next y reads
    }
    if (p < 32) outrow[(t + 1) * 32 + p] = y0;
  }
}

extern "C" void kernel_launch(void* const* d_in, const int* in_sizes, int n_in,
                              void* d_out, int out_size, void* d_ws, size_t ws_size,
                              hipStream_t stream) {
  const float* fp = (const float*)d_in[0];   // first_point [3,1024,32]
  const float* ts = (const float*)d_in[1];   // time_steps [256]
  const float* W1 = (const float*)d_in[2];   // [32,128]
  const float* b1 = (const float*)d_in[3];   // [128]
  const float* W2 = (const float*)d_in[4];   // [128,32]
  const float* b2 = (const float*)d_in[5];   // [32]
  float* out = (float*)d_out;                // [3,1024,256,32]

  rk4_ode_kernel<<<768, 256, 0, stream>>>(fp, ts, W1, b1, W2, b2, out);
}

// Round 14
// 790.802 us; speedup vs baseline: 1.5341x; 1.0417x over previous
//
#include <hip/hip_runtime.h>

// RK4 neural-ODE: f(y) = tanh(y W1 + b1) W2 + b2;  3072 rows x 255 steps.
// One wave per row, wave-synchronous. 768x256, waves_per_eu(3,3).
//
// ROUND 18 == ROUND 16/17 resubmit (neither ran: acquisition timeouts).
// SCALARIZE the weight FMAs (kill the AGPR copy tax at the ISA level).
// Evidence chain: R13 = 823.8us, VALU slots/eval = 246 vs ~126 hand
// count; gap ~120 == 128 v_accvgpr_read per eval (2 per f2 weight per
// v_pk_fma_f32). VOP3P cannot source AGPRs; VOP3 scalar v_fma_f32 CAN
// (CDNA2+). LLVM only forms pk_fma_f32 from <2 x float> IR, so scalar fmaf
// chains select copy-free v_fma_f32. pk has no f32 throughput advantage
// (157TF = 1 FMA/lane/cy), so 64 pk -> 128 scalar is slot-neutral and saves
// the 128 copies: 246 -> ~182 slots/eval.
// Accumulation order preserved EXACTLY (same even/odd chains, same sequence)
// => absmax must stay 0.015625.
// R13's LDS y-broadcast retained (it was -10%: readlane broadcast removed).
// Occupancy note: 25.9% = 2 waves/SIMD; total regs in (170,256]. If
// scalarization shrinks demand under 170, occupancy -> 37% and the 768-block
// 2-round serialization (512+256) disappears -- watch this counter.
// Predict: dur 560-680us. Refute: dur >= 800 -> next: inline-asm v_fma_f32
// with "a" constraints, or W2 -> LDS.

typedef float f2 __attribute__((ext_vector_type(2)));
typedef float f4 __attribute__((ext_vector_type(4)));

// tanh(z) with z pre-scaled by 2*log2(e): tanh = 1 - 2/(2^z + 1)
__device__ __forceinline__ float tanh_scaled(float z) {
  float t = __builtin_amdgcn_exp2f(z);
  return fmaf(-2.0f, __builtin_amdgcn_rcpf(t + 1.0f), 1.0f);
}
// quad_perm xor-1 / xor-2 (VALU-pipe cross-lane)
__device__ __forceinline__ float dpp_xor1(float x) {
  return __int_as_float(__builtin_amdgcn_update_dpp(
      0, __float_as_int(x), 0xB1, 0xF, 0xF, true));  // [1,0,3,2]
}
__device__ __forceinline__ float dpp_xor2(float x) {
  return __int_as_float(__builtin_amdgcn_update_dpp(
      0, __float_as_int(x), 0x4E, 0xF, 0xF, true));  // [2,3,0,1]
}

#define REP32(X) \
  X(0) X(1) X(2) X(3) X(4) X(5) X(6) X(7) X(8) X(9) X(10) X(11) X(12) X(13) \
  X(14) X(15) X(16) X(17) X(18) X(19) X(20) X(21) X(22) X(23) X(24) X(25)   \
  X(26) X(27) X(28) X(29) X(30) X(31)

__global__ void __launch_bounds__(256)
__attribute__((amdgpu_waves_per_eu(3, 3)))
rk4_ode_kernel(const float* __restrict__ fp,   // [3072,32]
               const float* __restrict__ ts,   // [256]
               const float* __restrict__ W1,   // [32,128]
               const float* __restrict__ b1,   // [128]
               const float* __restrict__ W2,   // [128,32]
               const float* __restrict__ b2,   // [32]
               float* __restrict__ out) {      // [3072,256,32]
  // per-wave: h buffer (8 chunks of 16 floats at stride 20, bank stagger)
  // + y broadcast buffer (32 floats)
  __shared__ float smem[4 * 160 + 4 * 32];

  const int tid = threadIdx.x;
  const int wv  = tid >> 6;
  const int p   = tid & 63;
  const int row = blockIdx.x * 4 + wv;

  const int g  = (p & 3) | ((p >> 5) << 2);   // j-group: lane bits {0,1,5}
  const int j0 = g << 4;                      // 16 j's per group
  const int d0 = p & 0x1C;                    // outputs d0|m, m=0..3

  const float C = 2.885390081777926814f;      // 2*log2(e) folded into W1/b1

  // ---- W1: lane p produces h_{2p}, h_{2p+1}; SCALAR col-pair regs ----
  const float2* W1v = reinterpret_cast<const float2*>(W1);
#define LOADW1(dd) float w1x_##dd, w1y_##dd; \
  { const float2 t_ = W1v[dd * 64 + p]; w1x_##dd = t_.x * C; w1y_##dd = t_.y * C; }
  REP32(LOADW1)
#undef LOADW1
  const float2 b1t = reinterpret_cast<const float2*>(b1)[p];
  const float b1x = b1t.x * C, b1y = b1t.y * C;

  // ---- W2: rows [j0, j0+16) for 4 outputs d0|m, SCALAR j-pair regs ----
  // w2a_m_i = W2[j0+2i][d0|m], w2b_m_i = W2[j0+2i+1][d0|m]
#define LW2(m) \
  const float w2a_##m##_0 = W2[(j0 + 0)  * 32 + (d0 | m)], w2b_##m##_0 = W2[(j0 + 1)  * 32 + (d0 | m)]; \
  const float w2a_##m##_1 = W2[(j0 + 2)  * 32 + (d0 | m)], w2b_##m##_1 = W2[(j0 + 3)  * 32 + (d0 | m)]; \
  const float w2a_##m##_2 = W2[(j0 + 4)  * 32 + (d0 | m)], w2b_##m##_2 = W2[(j0 + 5)  * 32 + (d0 | m)]; \
  const float w2a_##m##_3 = W2[(j0 + 6)  * 32 + (d0 | m)], w2b_##m##_3 = W2[(j0 + 7)  * 32 + (d0 | m)]; \
  const float w2a_##m##_4 = W2[(j0 + 8)  * 32 + (d0 | m)], w2b_##m##_4 = W2[(j0 + 9)  * 32 + (d0 | m)]; \
  const float w2a_##m##_5 = W2[(j0 + 10) * 32 + (d0 | m)], w2b_##m##_5 = W2[(j0 + 11) * 32 + (d0 | m)]; \
  const float w2a_##m##_6 = W2[(j0 + 12) * 32 + (d0 | m)], w2b_##m##_6 = W2[(j0 + 13) * 32 + (d0 | m)]; \
  const float w2a_##m##_7 = W2[(j0 + 14) * 32 + (d0 | m)], w2b_##m##_7 = W2[(j0 + 15) * 32 + (d0 | m)];
  LW2(0) LW2(1) LW2(2) LW2(3)
#undef LW2
  const float b2l = b2[p & 31];

  // ---- RK4 state: lane p holds dim d = p&31 (valid on all 64 lanes) ----
  float y0   = fp[row * 32 + (p & 31)];
  float ycur = y0;
  float kacc = 0.0f;

  float* outrow = out + (size_t)row * (256 * 32);
  if (p < 32) outrow[p] = y0;

  // h LDS addressing: h_j stored at float index 20*(j>>4) + (j&15)
  float* hwbase = &smem[wv * 160];
  float* hwr    = hwbase + 20 * (p >> 3) + 2 * (p & 7);   // write f2 (j=2p,2p+1)
  const f4* hrd = reinterpret_cast<const f4*>(hwbase + 20 * g); // 4x b128 reads
  // y broadcast buffer
  float* ybase  = &smem[640 + wv * 32];
  const f4* yrd = reinterpret_cast<const f4*>(ybase);
  const int pairaddr = (p ^ 32) << 2;

  // seed y broadcast (lanes p and p^32 write the same value: free 2-way dup)
  ybase[p & 31] = ycur;
  __builtin_amdgcn_wave_barrier();

  for (int t = 0; t < 255; ++t) {
    const float dt = ts[t + 1] - ts[t];
#pragma unroll
    for (int st = 0; st < 4; ++st) {
      // ---- phase 1: z = C*(b1 + y.W1) for cols 2p,2p+1 ----
      // y broadcast: 8 uniform ds_read_b128 (DS pipe)
      const f4 yv_0 = yrd[0]; const f4 yv_1 = yrd[1];
      const f4 yv_2 = yrd[2]; const f4 yv_3 = yrd[3];
      const f4 yv_4 = yrd[4]; const f4 yv_5 = yrd[5];
      const f4 yv_6 = yrd[6]; const f4 yv_7 = yrd[7];
      // 4 scalar chains (even/odd x column-pair), order identical to R13's
      // fma2 chains => bit-identical result, but v_fma_f32 (VOP3) can read
      // AGPR-resident weights directly -- no v_accvgpr_read copies.
      float aex = b1x, aox = 0.0f, aey = b1y, aoy = 0.0f;
#define P1E(s, dd) { aex = fmaf((s), w1x_##dd, aex); aey = fmaf((s), w1y_##dd, aey); }
#define P1O(s, dd) { aox = fmaf((s), w1x_##dd, aox); aoy = fmaf((s), w1y_##dd, aoy); }
      P1E(yv_0.x, 0)  P1O(yv_0.y, 1)  P1E(yv_0.z, 2)  P1O(yv_0.w, 3)
      P1E(yv_1.x, 4)  P1O(yv_1.y, 5)  P1E(yv_1.z, 6)  P1O(yv_1.w, 7)
      P1E(yv_2.x, 8)  P1O(yv_2.y, 9)  P1E(yv_2.z, 10) P1O(yv_2.w, 11)
      P1E(yv_3.x, 12) P1O(yv_3.y, 13) P1E(yv_3.z, 14) P1O(yv_3.w, 15)
      P1E(yv_4.x, 16) P1O(yv_4.y, 17) P1E(yv_4.z, 18) P1O(yv_4.w, 19)
      P1E(yv_5.x, 20) P1O(yv_5.y, 21) P1E(yv_5.z, 22) P1O(yv_5.w, 23)
      P1E(yv_6.x, 24) P1O(yv_6.y, 25) P1E(yv_6.z, 26) P1O(yv_6.w, 27)
      P1E(yv_7.x, 28) P1O(yv_7.y, 29) P1E(yv_7.z, 30) P1O(yv_7.w, 31)
#undef P1E
#undef P1O
      const float ax = aex + aox;
      const float ay = aey + aoy;
      *reinterpret_cast<f2*>(hwr) = (f2){tanh_scaled(ax), tanh_scaled(ay)};
      __builtin_amdgcn_wave_barrier();          // h write before h reads

      // ---- phase 2: 16 h-floats for my j-group vs 4 output columns ----
      float accx0 = 0, accy0 = 0, accx1 = 0, accy1 = 0;
      float accx2 = 0, accy2 = 0, accx3 = 0, accy3 = 0;
      {
        const f4 r_0 = hrd[0], r_1 = hrd[1];
#define ACCA(m) accx##m = fmaf(r_0.x, w2a_##m##_0, accx##m); \
                accy##m = fmaf(r_0.y, w2b_##m##_0, accy##m); \
                accx##m = fmaf(r_0.z, w2a_##m##_1, accx##m); \
                accy##m = fmaf(r_0.w, w2b_##m##_1, accy##m); \
                accx##m = fmaf(r_1.x, w2a_##m##_2, accx##m); \
                accy##m = fmaf(r_1.y, w2b_##m##_2, accy##m); \
                accx##m = fmaf(r_1.z, w2a_##m##_3, accx##m); \
                accy##m = fmaf(r_1.w, w2b_##m##_3, accy##m);
        ACCA(0) ACCA(1) ACCA(2) ACCA(3)
#undef ACCA
        const f4 r_2 = hrd[2], r_3 = hrd[3];
#define ACCB(m) accx##m = fmaf(r_2.x, w2a_##m##_4, accx##m); \
                accy##m = fmaf(r_2.y, w2b_##m##_4, accy##m); \
                accx##m = fmaf(r_2.z, w2a_##m##_5, accx##m); \
                accy##m = fmaf(r_2.w, w2b_##m##_5, accy##m); \
                accx##m = fmaf(r_3.x, w2a_##m##_6, accx##m); \
                accy##m = fmaf(r_3.y, w2b_##m##_6, accy##m); \
                accx##m = fmaf(r_3.z, w2a_##m##_7, accx##m); \
                accy##m = fmaf(r_3.w, w2b_##m##_7, accy##m);
        ACCB(0) ACCB(1) ACCB(2) ACCB(3)
#undef ACCB
      }
      __builtin_amdgcn_wave_barrier();          // h reads before next h write

      // ---- combine group partials: ^1,^2 via DPP (VALU), select, then ^32 ----
      float k0 = accx0 + accy0, k1 = accx1 + accy1;
      float k2 = accx2 + accy2, k3 = accx3 + accy3;
      k0 += dpp_xor1(k0); k1 += dpp_xor1(k1); k2 += dpp_xor1(k2); k3 += dpp_xor1(k3);
      k0 += dpp_xor2(k0); k1 += dpp_xor2(k1); k2 += dpp_xor2(k2); k3 += dpp_xor2(k3);
      const float s01 = (p & 1) ? k1 : k0;
      const float s23 = (p & 1) ? k3 : k2;
      const float ks  = (p & 2) ? s23 : s01;    // my output's quad partial
      const float k = ks + b2l + __int_as_float(
          __builtin_amdgcn_ds_bpermute(pairaddr, __float_as_int(ks)));

      // ---- RK4 stage combination ----
      if (st == 0) {
        kacc = k;                   ycur = fmaf(0.5f * dt, k, y0);
      } else if (st == 1) {
        kacc = fmaf(2.0f, k, kacc); ycur = fmaf(0.5f * dt, k, y0);
      } else if (st == 2) {
        kacc = fmaf(2.0f, k, kacc); ycur = fmaf(dt, k, y0);
      } else {
        kacc = kacc + k;
        y0   = fmaf(dt * (1.0f / 6.0f), kacc, y0);
        ycur = y0;
      }

      // publish y for next stage's broadcast (2-way same-addr dup: free)
      ybase[p & 31] = ycur;
      __builtin_amdgcn_wave_barrier();          // y write before next y reads
    }
    if (p < 32) outrow[(t + 1) * 32 + p] = y0;
  }
}

extern "C" void kernel_launch(void* const* d_in, const int* in_sizes, int n_in,
                              void* d_out, int out_size, void* d_ws, size_t ws_size,
                              hipStream_t stream) {
  const float* fp = (const float*)d_in[0];   // first_point [3,1024,32]
  const float* ts = (const float*)d_in[1];   // time_steps [256]
  const float* W1 = (const float*)d_in[2];   // [32,128]
  const float* b1 = (const float*)d_in[3];   // [128]
  const float* W2 = (const float*)d_in[4];   // [128,32]
  const float* b2 = (const float*)d_in[5];   // [32]
  float* out = (float*)d_out;                // [3,1024,256,32]

  rk4_ode_kernel<<<768, 256, 0, stream>>>(fp, ts, W1, b1, W2, b2, out);
}